// Round 4
// baseline (41.180 us; speedup 1.0000x reference)
//
#include <hip/hip_runtime.h>
#include <hip/hip_fp16.h>
#include <hip/hip_bf16.h>

#define OUTF 11008
#define INF  4096

typedef unsigned int uint;
typedef __attribute__((ext_vector_type(8))) short bf16x8;   // 8 bf16 = 4 VGPR (MFMA A/B)
typedef __attribute__((ext_vector_type(4))) float f32x4;    // MFMA C/D

union U4 { uint u[4]; bf16x8 v; };

__device__ __forceinline__ uint pack_bf162(float lo, float hi) {
  union { __hip_bfloat162 h; uint u; } cvt;
  cvt.h = __float22bfloat162_rn(make_float2(lo, hi));
  return cvt.u;
}

__global__ __launch_bounds__(256) void lin2bit_kernel(
    const float* __restrict__ x, const int* __restrict__ wq,
    const float* __restrict__ wn, const float* __restrict__ bias,
    float* __restrict__ out)
{
  __shared__ float red[1024];
  const int tid = threadIdx.x;
  const int wv  = tid >> 6;          // wave 0..3: K-split, groups [wv*32, wv*32+32)
  const int l   = tid & 63;
  const int col = l & 15;            // A-row (m) / B-col (o)
  const int q   = l >> 4;            // k-quad: this lane covers k = 8q..8q+7 of each group
  const int o0  = (int)blockIdx.x << 4;

  const int    orow  = o0 + col;
  const size_t gbase = (size_t)orow * 128 + (size_t)(wv * 32);       // first group idx
  const char*  wp    = (const char*)wq + gbase * 32 + q * 8;          // 32 B per group
  const float* npr   = wn + gbase;                                    // 32 norms (f32!)
  const float* xp    = x + (size_t)col * INF + wv * 1024 + q * 8;

  f32x4 acc = {0.f, 0.f, 0.f, 0.f};

#pragma unroll 1
  for (int s = 0; s < 4; ++s) {
    const float4 nA = *(const float4*)(npr + s * 8);
    const float4 nB = *(const float4*)(npr + s * 8 + 4);
    const float n8[8] = {nA.x, nA.y, nA.z, nA.w, nB.x, nB.y, nB.z, nB.w};
#pragma unroll
    for (int j = 0; j < 8; ++j) {
      // B: 8 codes (group elements 8q..8q+7) = 2 int32 low bytes
      const uint2 p = *(const uint2*)(wp + s * 256 + j * 32);
      const float nv  = n8[j];
      const float nv3 = nv * 0.333f;
      // 64-bit table: code c -> bf16 weight at bits [16c,16c+16): {-nv,-nv3,+nv3,+nv}
      const unsigned long long T =
          ((unsigned long long)pack_bf162(nv3, nv) << 32) |
          (unsigned long long)pack_bf162(-nv, -nv3);
      const uint p0 = p.x << 4, p1 = p.y << 4;
      const uint w0 = (uint)(T >> (p0 & 0x30u));
      const uint w1 = (uint)(T >> ((p0 >> 2) & 0x30u));
      const uint w2 = (uint)(T >> ((p0 >> 4) & 0x30u));
      const uint w3 = (uint)(T >> ((p0 >> 6) & 0x30u));
      const uint w4 = (uint)(T >> (p1 & 0x30u));
      const uint w5 = (uint)(T >> ((p1 >> 2) & 0x30u));
      const uint w6 = (uint)(T >> ((p1 >> 4) & 0x30u));
      const uint w7 = (uint)(T >> ((p1 >> 6) & 0x30u));
      U4 B;
      B.u[0] = (w0 & 0xFFFFu) | (w1 << 16);
      B.u[1] = (w2 & 0xFFFFu) | (w3 << 16);
      B.u[2] = (w4 & 0xFFFFu) | (w5 << 16);
      B.u[3] = (w6 & 0xFFFFu) | (w7 << 16);
      // A: x[m][same 8 k's], f32 -> bf16
      const float4 xa = *(const float4*)(xp + s * 256 + j * 32);
      const float4 xb = *(const float4*)(xp + s * 256 + j * 32 + 4);
      U4 A;
      A.u[0] = pack_bf162(xa.x, xa.y);
      A.u[1] = pack_bf162(xa.z, xa.w);
      A.u[2] = pack_bf162(xb.x, xb.y);
      A.u[3] = pack_bf162(xb.z, xb.w);
      acc = __builtin_amdgcn_mfma_f32_16x16x32_bf16(A.v, B.v, acc, 0, 0, 0);
    }
  }

  // ---- cross-wave K reduction + bias + store
  red[wv * 256 +   0 + l] = acc[0];
  red[wv * 256 +  64 + l] = acc[1];
  red[wv * 256 + 128 + l] = acc[2];
  red[wv * 256 + 192 + l] = acc[3];
  __syncthreads();
  const int t = tid;
  const float s = red[t] + red[256 + t] + red[512 + t] + red[768 + t];
  const int m  = ((t & 63) >> 4) * 4 + (t >> 6);   // D row = (lane>>4)*4 + reg
  const int oc = t & 15;                            // D col = lane & 15
  out[(size_t)m * OUTF + o0 + oc] = s + bias[o0 + oc];
}

extern "C" void kernel_launch(void* const* d_in, const int* in_sizes, int n_in,
                              void* d_out, int out_size, void* d_ws, size_t ws_size,
                              hipStream_t stream) {
  (void)in_sizes; (void)n_in; (void)out_size; (void)d_ws; (void)ws_size;
  const float* x    = (const float*)d_in[0];
  const int*   wq   = (const int*)d_in[1];
  const float* wn   = (const float*)d_in[2];
  const float* bias = (const float*)d_in[3];
  float*       out  = (float*)d_out;
  lin2bit_kernel<<<dim3(OUTF / 16), dim3(256), 0, stream>>>(x, wq, wn, bias, out);
}